// Round 1
// baseline (6182.240 us; speedup 1.0000x reference)
//
#include <hip/hip_runtime.h>
#include <math.h>

#define BB 8
#define NN 1024
#define CC 16
#define SS 32
#define LLAYERS 8
#define HH 8
#define TK 128

// Blade metadata (reference blade ordering):
// 0:() 1:(0) 2:(1) 3:(2) 4:(3) 5:(01) 6:(02) 7:(03) 8:(12) 9:(13) 10:(23)
// 11:(012) 12:(013) 13:(023) 14:(123) 15:(0123)
__constant__ int d_GRADE[16] = {0,1,1,1,1,2,2,2,2,2,2,3,3,3,3,4};
__constant__ int d_PAIR[16]  = {-1,0,-1,-1,-1,2,3,4,-1,-1,-1,8,9,10,-1,14};
__constant__ int d_INNER[16] = {1,0,1,1,1,0,0,0,1,1,1,0,0,0,1,0};
// blade index -> bitmask over {e0,e1,e2,e3}
__constant__ int d_I2M[16] = {0,1,2,4,8,3,5,9,6,10,12,7,11,13,14,15};
// bitmask -> blade index
__constant__ int d_M2I[16] = {0,1,2,5,3,6,8,11,4,7,9,12,10,13,14,15};

__device__ __forceinline__ float gelu_tanh(float x) {
  // jax.nn.gelu approximate=True
  float x3 = x * x * x;
  float inner = 0.7978845608028654f * (x + 0.044715f * x3);
  return 0.5f * x * (1.0f + tanhf(inner));
}

// ---------------- embed ----------------
// mv0: idx14=1, idx13=-x, idx12=y, idx11=-z (all grade 3); others 0.
// mv[o,a] = win_mv[o,0,grade(a)]*mv0[a] + (pair) win_mv[o,0,4+grade(a)]*mv0[pair(a)]
// s = win_bs (win_ms term multiplies mv0 blade0 == 0)
__global__ void __launch_bounds__(256) k_embed(
    const float* __restrict__ inp, const float* __restrict__ win_mv,
    const float* __restrict__ win_ms, const float* __restrict__ win_bs,
    float* __restrict__ mv, float* __restrict__ s)
{
  int tok = blockIdx.x, t = threadIdx.x;
  float x = inp[tok * 3 + 0];
  float y = inp[tok * 3 + 1];
  float z = inp[tok * 3 + 2];
  int o = t >> 4, aa = t & 15;
  float ma = (aa == 14) ? 1.f : (aa == 13) ? -x : (aa == 12) ? y : (aa == 11) ? -z : 0.f;
  int g = d_GRADE[aa];
  float val = win_mv[o * 9 + g] * ma;
  int pr = d_PAIR[aa];
  if (pr >= 0) {
    float mp = (pr == 14) ? 1.f : 0.f;  // other pair blades are zero in mv0
    val += win_mv[o * 9 + 4 + g] * mp;
  }
  mv[(size_t)tok * 256 + t] = val;
  if (t < 32) s[(size_t)tok * 32 + t] = win_bs[t];
  (void)win_ms;
}

// ---------------- LN + QKV projection ----------------
__global__ void __launch_bounds__(256) k_ln_qkv(
    const float* __restrict__ mv, const float* __restrict__ s,
    const float* __restrict__ wmv, const float* __restrict__ wsm,
    const float* __restrict__ wms, const float* __restrict__ wss,
    float* __restrict__ qkv_mv, float* __restrict__ qkv_s)
{
  __shared__ float nmv[256];
  __shared__ float ns[32];
  __shared__ float red[256];
  int tok = blockIdx.x, t = threadIdx.x;
  int aa = t & 15;
  float v = mv[(size_t)tok * 256 + t];
  float sv = (t < 32) ? s[(size_t)tok * 32 + t] : 0.f;
  red[t] = d_INNER[aa] ? v * v : 0.f;
  __syncthreads();
  for (int w = 128; w > 0; w >>= 1) { if (t < w) red[t] += red[t + w]; __syncthreads(); }
  float inv = rsqrtf(red[0] / 16.f + 1e-6f);
  __syncthreads();
  red[t] = (t < 32) ? sv * sv : 0.f;
  __syncthreads();
  for (int w = 128; w > 0; w >>= 1) { if (t < w) red[t] += red[t + w]; __syncthreads(); }
  float sinv = rsqrtf(red[0] / 32.f + 1e-6f);
  nmv[t] = v * inv;
  if (t < 32) ns[t] = sv * sinv;
  __syncthreads();

  size_t qbase = (size_t)tok * 768;
  for (int r = 0; r < 3; ++r) {
    int u = r * 256 + t;
    int o = u >> 4, a2 = u & 15;
    int g = d_GRADE[a2];
    const float* w = wmv + (size_t)o * 16 * 9;
    float yy = 0.f;
    #pragma unroll
    for (int i = 0; i < 16; ++i) yy += w[i * 9 + g] * nmv[i * 16 + a2];
    int pr = d_PAIR[a2];
    if (pr >= 0) {
      int k2 = 4 + g;
      #pragma unroll
      for (int i = 0; i < 16; ++i) yy += w[i * 9 + k2] * nmv[i * 16 + pr];
    }
    if (a2 == 0) {
      const float* wr = wsm + (size_t)o * 32;
      #pragma unroll
      for (int j = 0; j < 32; ++j) yy += wr[j] * ns[j];
    }
    qkv_mv[qbase + u] = yy;
  }
  if (t < 96) {
    float yy = 0.f;
    const float* w1 = wss + (size_t)t * 32;
    #pragma unroll
    for (int j = 0; j < 32; ++j) yy += w1[j] * ns[j];
    const float* w2 = wms + (size_t)t * 16;
    #pragma unroll
    for (int i = 0; i < 16; ++i) yy += w2[i] * nmv[i * 16];
    qkv_s[(size_t)tok * 96 + t] = yy;
  }
}

// ---------------- attention ----------------
// one thread = one query; flash-style online softmax over key tiles in LDS.
__global__ void __launch_bounds__(256) k_attn(
    const float* __restrict__ qkv_mv, const float* __restrict__ qkv_s,
    float* __restrict__ o_mv, float* __restrict__ o_s)
{
  __shared__ __align__(16) float kb[TK * 36];
  __shared__ __align__(16) float vb[TK * 36];
  int bx = blockIdx.x;
  int qt = bx & 3, h = (bx >> 2) & 7, b = bx >> 5;
  int t = threadIdx.x;
  int n = qt * 256 + t;
  const float scale = 0.22360679774997896f;  // 1/sqrt(8*2 + 4)

  float qr[36];
  {
    const float* qp = qkv_mv + ((size_t)(b * NN + n) * 48 + 2 * h) * 16;
    #pragma unroll
    for (int u = 0; u < 32; ++u) qr[u] = d_INNER[u & 15] ? qp[u] * scale : 0.f;
    const float* qsp = qkv_s + (size_t)(b * NN + n) * 96 + 4 * h;
    #pragma unroll
    for (int d = 0; d < 4; ++d) qr[32 + d] = qsp[d] * scale;
  }

  float4 acc[9];
  #pragma unroll
  for (int u = 0; u < 9; ++u) acc[u] = make_float4(0.f, 0.f, 0.f, 0.f);
  float mrun = -1e30f, lrun = 0.f;

  for (int kt = 0; kt < NN / TK; ++kt) {
    __syncthreads();
    // cooperative K/V tile load: k_mv 32 + k_s 4 = 36 floats per key
    #pragma unroll
    for (int it = 0; it < 4; ++it) {
      int idx = it * 256 + t;
      int m = idx >> 3, p = idx & 7;
      int kg = kt * TK + m;
      const float4* srck = (const float4*)(qkv_mv + ((size_t)(b * NN + kg) * 48 + 16 + 2 * h) * 16 + p * 4);
      *(float4*)&kb[m * 36 + p * 4] = *srck;
      const float4* srcv = (const float4*)(qkv_mv + ((size_t)(b * NN + kg) * 48 + 32 + 2 * h) * 16 + p * 4);
      *(float4*)&vb[m * 36 + p * 4] = *srcv;
    }
    {
      int m = t & 127;
      int kg = kt * TK + m;
      if (t < 128) {
        *(float4*)&kb[m * 36 + 32] = *(const float4*)(qkv_s + (size_t)(b * NN + kg) * 96 + 32 + 4 * h);
      } else {
        *(float4*)&vb[m * 36 + 32] = *(const float4*)(qkv_s + (size_t)(b * NN + kg) * 96 + 64 + 4 * h);
      }
    }
    __syncthreads();

    for (int m = 0; m < TK; ++m) {
      const float4* kp = (const float4*)&kb[m * 36];
      float sc = 0.f;
      #pragma unroll
      for (int u = 0; u < 9; ++u) {
        float4 kv = kp[u];
        sc += qr[u * 4 + 0] * kv.x + qr[u * 4 + 1] * kv.y + qr[u * 4 + 2] * kv.z + qr[u * 4 + 3] * kv.w;
      }
      float nm = fmaxf(mrun, sc);
      float corr = __expf(mrun - nm);
      float p = __expf(sc - nm);
      mrun = nm;
      lrun = lrun * corr + p;
      const float4* vp = (const float4*)&vb[m * 36];
      #pragma unroll
      for (int u = 0; u < 9; ++u) {
        float4 vv = vp[u];
        acc[u].x = acc[u].x * corr + p * vv.x;
        acc[u].y = acc[u].y * corr + p * vv.y;
        acc[u].z = acc[u].z * corr + p * vv.z;
        acc[u].w = acc[u].w * corr + p * vv.w;
      }
    }
  }

  float invl = 1.f / lrun;
  float* op = o_mv + ((size_t)(b * NN + n) * 16 + 2 * h) * 16;
  #pragma unroll
  for (int u = 0; u < 8; ++u) {
    float4 av = acc[u];
    av.x *= invl; av.y *= invl; av.z *= invl; av.w *= invl;
    *(float4*)(op + u * 4) = av;
  }
  float* osp = o_s + (size_t)(b * NN + n) * 32 + 4 * h;
  osp[0] = acc[8].x * invl;
  osp[1] = acc[8].y * invl;
  osp[2] = acc[8].z * invl;
  osp[3] = acc[8].w * invl;
}

// ---------------- attention out-proj + residual ----------------
__global__ void __launch_bounds__(256) k_out_res(
    const float* __restrict__ o_mv, const float* __restrict__ o_s,
    const float* __restrict__ wmv, const float* __restrict__ wsm,
    const float* __restrict__ wms, const float* __restrict__ wss,
    float* __restrict__ mv, float* __restrict__ s)
{
  __shared__ float x[256];
  __shared__ float xs[32];
  int tok = blockIdx.x, t = threadIdx.x;
  x[t] = o_mv[(size_t)tok * 256 + t];
  if (t < 32) xs[t] = o_s[(size_t)tok * 32 + t];
  __syncthreads();
  int o = t >> 4, aa = t & 15;
  int g = d_GRADE[aa];
  const float* w = wmv + (size_t)o * 16 * 9;
  float yy = 0.f;
  #pragma unroll
  for (int i = 0; i < 16; ++i) yy += w[i * 9 + g] * x[i * 16 + aa];
  int pr = d_PAIR[aa];
  if (pr >= 0) {
    int k2 = 4 + g;
    #pragma unroll
    for (int i = 0; i < 16; ++i) yy += w[i * 9 + k2] * x[i * 16 + pr];
  }
  if (aa == 0) {
    const float* wr = wsm + (size_t)o * 32;
    #pragma unroll
    for (int j = 0; j < 32; ++j) yy += wr[j] * xs[j];
  }
  mv[(size_t)tok * 256 + t] += yy;
  if (t < 32) {
    float ys = 0.f;
    const float* w1 = wss + (size_t)t * 32;
    #pragma unroll
    for (int j = 0; j < 32; ++j) ys += w1[j] * xs[j];
    const float* w2 = wms + (size_t)t * 16;
    #pragma unroll
    for (int i = 0; i < 16; ++i) ys += w2[i] * x[i * 16];
    s[(size_t)tok * 32 + t] += ys;
  }
}

// ---------------- LN + geometric MLP + residual ----------------
__global__ void __launch_bounds__(256) k_mlp_res(
    float* __restrict__ mv, float* __restrict__ s,
    const float* __restrict__ w1mv, const float* __restrict__ w1sm,
    const float* __restrict__ w1ms, const float* __restrict__ w1ss,
    const float* __restrict__ w2mv, const float* __restrict__ w2sm,
    const float* __restrict__ w2ms, const float* __restrict__ w2ss)
{
  __shared__ float nmv[256];
  __shared__ float ns[32];
  __shared__ float red[256];
  __shared__ float hmv[512];
  __shared__ float hs[64];
  __shared__ float gpl[256];
  __shared__ float shl[32];
  int tok = blockIdx.x, t = threadIdx.x;
  int aa = t & 15;
  float v = mv[(size_t)tok * 256 + t];
  float sv = (t < 32) ? s[(size_t)tok * 32 + t] : 0.f;
  red[t] = d_INNER[aa] ? v * v : 0.f;
  __syncthreads();
  for (int w = 128; w > 0; w >>= 1) { if (t < w) red[t] += red[t + w]; __syncthreads(); }
  float inv = rsqrtf(red[0] / 16.f + 1e-6f);
  __syncthreads();
  red[t] = (t < 32) ? sv * sv : 0.f;
  __syncthreads();
  for (int w = 128; w > 0; w >>= 1) { if (t < w) red[t] += red[t + w]; __syncthreads(); }
  float sinv = rsqrtf(red[0] / 32.f + 1e-6f);
  nmv[t] = v * inv;
  if (t < 32) ns[t] = sv * sinv;
  __syncthreads();

  // h = equi_linear1: 32 mv channels, 64 s
  for (int r = 0; r < 2; ++r) {
    int u = r * 256 + t;
    int o = u >> 4, a2 = u & 15;
    int g = d_GRADE[a2];
    const float* w = w1mv + (size_t)o * 16 * 9;
    float yy = 0.f;
    #pragma unroll
    for (int i = 0; i < 16; ++i) yy += w[i * 9 + g] * nmv[i * 16 + a2];
    int pr = d_PAIR[a2];
    if (pr >= 0) {
      int k2 = 4 + g;
      #pragma unroll
      for (int i = 0; i < 16; ++i) yy += w[i * 9 + k2] * nmv[i * 16 + pr];
    }
    if (a2 == 0) {
      const float* wr = w1sm + (size_t)o * 32;
      #pragma unroll
      for (int j = 0; j < 32; ++j) yy += wr[j] * ns[j];
    }
    hmv[u] = yy;
  }
  if (t < 64) {
    float yy = 0.f;
    const float* w1 = w1ss + (size_t)t * 32;
    #pragma unroll
    for (int j = 0; j < 32; ++j) yy += w1[j] * ns[j];
    const float* w2 = w1ms + (size_t)t * 16;
    #pragma unroll
    for (int i = 0; i < 16; ++i) yy += w2[i] * nmv[i * 16];
    hs[t] = yy;
  }
  __syncthreads();

  // geometric product gp[c,k] = sum_i sign(i,j)*h1[c,i]*h2[c,j], j = idx(mask_i ^ mask_k)
  int c = t >> 4, k = t & 15;
  int mk = d_I2M[k];
  float gacc = 0.f;
  #pragma unroll
  for (int i = 0; i < 16; ++i) {
    int mi = d_I2M[i];
    int mj = mi ^ mk;
    if (mi & mj & 1) continue;  // e0 * e0 = 0
    int j = d_M2I[mj];
    int sw = 0;
    #pragma unroll
    for (int bb = 0; bb < 4; ++bb)
      if (mj & (1 << bb)) sw += __popc(((unsigned)mi) >> (bb + 1));
    float val = hmv[c * 16 + i] * hmv[256 + c * 16 + j];
    gacc += (sw & 1) ? -val : val;
  }
  gpl[t] = gacc;
  __syncthreads();
  float g0 = gpl[c * 16];
  __syncthreads();
  gpl[t] = gacc * gelu_tanh(g0);
  if (t < 32) shl[t] = hs[t] * gelu_tanh(hs[32 + t]);
  __syncthreads();

  // equi_linear2 + residual
  {
    int o = t >> 4;
    int g = d_GRADE[aa];
    const float* w = w2mv + (size_t)o * 16 * 9;
    float yy = 0.f;
    #pragma unroll
    for (int i = 0; i < 16; ++i) yy += w[i * 9 + g] * gpl[i * 16 + aa];
    int pr = d_PAIR[aa];
    if (pr >= 0) {
      int k2 = 4 + g;
      #pragma unroll
      for (int i = 0; i < 16; ++i) yy += w[i * 9 + k2] * gpl[i * 16 + pr];
    }
    if (aa == 0) {
      const float* wr = w2sm + (size_t)o * 32;
      #pragma unroll
      for (int j = 0; j < 32; ++j) yy += wr[j] * shl[j];
    }
    mv[(size_t)tok * 256 + t] = v + yy;
  }
  if (t < 32) {
    float ys = 0.f;
    const float* w1 = w2ss + (size_t)t * 32;
    #pragma unroll
    for (int j = 0; j < 32; ++j) ys += w1[j] * shl[j];
    const float* w2 = w2ms + (size_t)t * 16;
    #pragma unroll
    for (int i = 0; i < 16; ++i) ys += w2[i] * gpl[i * 16];
    s[(size_t)tok * 32 + t] = sv + ys;
  }
}

// ---------------- final projection + mean ----------------
__global__ void __launch_bounds__(256) k_final(
    const float* __restrict__ mv, const float* __restrict__ s,
    const float* __restrict__ wout_mv, const float* __restrict__ wout_sm,
    float* __restrict__ out)
{
  __shared__ float red[256];
  int b = blockIdx.x, t = threadIdx.x;
  float part = 0.f;
  for (int n = t; n < NN; n += 256) {
    const float* mvp = mv + ((size_t)(b * NN + n) * 16) * 16;
    const float* sp = s + (size_t)(b * NN + n) * 32;
    float acc = 0.f;
    #pragma unroll
    for (int i = 0; i < 16; ++i) acc += wout_mv[i * 9] * mvp[i * 16];
    #pragma unroll
    for (int j = 0; j < 32; ++j) acc += wout_sm[j] * sp[j];
    part += acc;
  }
  red[t] = part;
  __syncthreads();
  for (int w = 128; w > 0; w >>= 1) { if (t < w) red[t] += red[t + w]; __syncthreads(); }
  if (t == 0) out[b] = red[0] / (float)NN;
}

extern "C" void kernel_launch(void* const* d_in, const int* in_sizes, int n_in,
                              void* d_out, int out_size, void* d_ws, size_t ws_size,
                              hipStream_t stream) {
  const float* inputs    = (const float*)d_in[0];
  const float* win_mv    = (const float*)d_in[1];
  const float* win_ms    = (const float*)d_in[2];
  const float* win_bs    = (const float*)d_in[3];
  const float* a_qkv_wmv = (const float*)d_in[4];
  const float* a_qkv_wsm = (const float*)d_in[5];
  const float* a_qkv_wms = (const float*)d_in[6];
  const float* a_qkv_wss = (const float*)d_in[7];
  const float* a_out_wmv = (const float*)d_in[8];
  const float* a_out_wsm = (const float*)d_in[9];
  const float* a_out_wms = (const float*)d_in[10];
  const float* a_out_wss = (const float*)d_in[11];
  const float* m1_wmv    = (const float*)d_in[12];
  const float* m1_wsm    = (const float*)d_in[13];
  const float* m1_wms    = (const float*)d_in[14];
  const float* m1_wss    = (const float*)d_in[15];
  const float* m2_wmv    = (const float*)d_in[16];
  const float* m2_wsm    = (const float*)d_in[17];
  const float* m2_wms    = (const float*)d_in[18];
  const float* m2_wss    = (const float*)d_in[19];
  const float* wout_mv   = (const float*)d_in[20];
  const float* wout_sm   = (const float*)d_in[21];
  float* out = (float*)d_out;

  float* ws = (float*)d_ws;
  float* mv     = ws;                    // 8*1024*16*16 = 2097152
  float* s      = mv + 2097152;          // 8*1024*32    = 262144
  float* qkv_mv = s + 262144;            // 8*1024*48*16 = 6291456
  float* qkv_s  = qkv_mv + 6291456;      // 8*1024*96    = 786432
  float* o_mv   = qkv_s + 786432;        // 2097152
  float* o_s    = o_mv + 2097152;        // 262144

  int ntok = BB * NN;
  k_embed<<<ntok, 256, 0, stream>>>(inputs, win_mv, win_ms, win_bs, mv, s);

  for (int l = 0; l < LLAYERS; ++l) {
    k_ln_qkv<<<ntok, 256, 0, stream>>>(mv, s,
        a_qkv_wmv + (size_t)l * 48 * 16 * 9, a_qkv_wsm + (size_t)l * 48 * 32,
        a_qkv_wms + (size_t)l * 96 * 16,     a_qkv_wss + (size_t)l * 96 * 32,
        qkv_mv, qkv_s);
    k_attn<<<BB * HH * 4, 256, 0, stream>>>(qkv_mv, qkv_s, o_mv, o_s);
    k_out_res<<<ntok, 256, 0, stream>>>(o_mv, o_s,
        a_out_wmv + (size_t)l * 16 * 16 * 9, a_out_wsm + (size_t)l * 16 * 32,
        a_out_wms + (size_t)l * 32 * 16,     a_out_wss + (size_t)l * 32 * 32,
        mv, s);
    k_mlp_res<<<ntok, 256, 0, stream>>>(mv, s,
        m1_wmv + (size_t)l * 32 * 16 * 9, m1_wsm + (size_t)l * 32 * 32,
        m1_wms + (size_t)l * 64 * 16,     m1_wss + (size_t)l * 64 * 32,
        m2_wmv + (size_t)l * 16 * 16 * 9, m2_wsm + (size_t)l * 16 * 32,
        m2_wms + (size_t)l * 32 * 16,     m2_wss + (size_t)l * 32 * 32);
  }

  k_final<<<BB, 256, 0, stream>>>(mv, s, wout_mv, wout_sm, out);

  (void)in_sizes; (void)n_in; (void)out_size; (void)ws_size;
}